// Round 1
// baseline (655.128 us; speedup 1.0000x reference)
//
#include <hip/hip_runtime.h>
#include <hip/hip_bf16.h>

// Problem constants
#define B_    64
#define S_    512
#define H_    1024
#define T_    4
#define NF_   12
#define TNF_  48      // T*NF
#define NP_   66      // NF*(NF-1)/2
#define OUTC_ 127     // 1 + 48 + 66 + 12

// workspace layout (in floats)
#define OFF_TGT    0
#define OFF_FCT    (OFF_TGT + B_*T_*H_)        // 262144
#define OFF_TSIDE  (OFF_FCT + B_*NF_*H_)       // 1048576
#define OFF_SSENT  (OFF_TSIDE + B_*H_)         // 1114112
#define OFF_SSTEP  (OFF_SSENT + B_*TNF_)
#define OFF_SABD   (OFF_SSTEP + B_*NP_)
#define OFF_SCLS   (OFF_SABD + B_*NF_)
#define SCORE_TOTAL (B_*TNF_ + B_*NP_ + B_*NF_ + B_)

// ---------------------------------------------------------------------------
// Segment means: one block per (b, segment). tgt (B,T,H), fct (B,NF,H)
// ---------------------------------------------------------------------------
__global__ __launch_bounds__(256) void seg_mean_kernel(
    const float* __restrict__ seq, const int* __restrict__ toffs,
    const int* __restrict__ foffs, float* __restrict__ tgt,
    float* __restrict__ fct)
{
    int blk = blockIdx.x;
    int b = blk >> 4;
    int k = blk & 15;
    int start, end;
    float* dst;
    if (k < T_) {
        start = toffs[(b*T_ + k)*2];
        end   = toffs[(b*T_ + k)*2 + 1];
        dst   = tgt + (size_t)(b*T_ + k) * H_;
    } else {
        int f = k - T_;
        start = foffs[(b*NF_ + f)*2];
        end   = foffs[(b*NF_ + f)*2 + 1];
        dst   = fct + (size_t)(b*NF_ + f) * H_;
    }
    int h0 = threadIdx.x * 4;
    const float* base = seq + ((size_t)b * S_ + start) * H_ + h0;
    float4 s = make_float4(0.f, 0.f, 0.f, 0.f);
    int n = end - start;
    for (int r = 0; r < n; ++r) {
        float4 v = *(const float4*)(base + (size_t)r * H_);
        s.x += v.x; s.y += v.y; s.z += v.z; s.w += v.w;
    }
    float inv = 1.f / (float)n;
    *(float4*)(dst + h0) = make_float4(s.x*inv, s.y*inv, s.z*inv, s.w*inv);
}

// tside = mean over T of tgt  -> (B, H)
__global__ __launch_bounds__(256) void tside_kernel(
    const float* __restrict__ tgt, float* __restrict__ tside)
{
    int b = blockIdx.x;
    int h0 = threadIdx.x * 4;
    float4 s = make_float4(0.f, 0.f, 0.f, 0.f);
    for (int t = 0; t < T_; ++t) {
        float4 v = *(const float4*)(tgt + (size_t)(b*T_ + t)*H_ + h0);
        s.x += v.x; s.y += v.y; s.z += v.z; s.w += v.w;
    }
    *(float4*)(tside + (size_t)b*H_ + h0) =
        make_float4(s.x*0.25f, s.y*0.25f, s.z*0.25f, s.w*0.25f);
}

// ---------------------------------------------------------------------------
// Fused MLP-head GEMM: score[r] += sum_n relu( (x_r . W1[:,n]) + b1[n] )*w2[n]
// X rows gathered on the fly from pooled features (never materialized).
// BM=BN=64, BK=16, 256 threads, 4x4 per-thread microtile.
// HEAD: 0=sentsim, 1=step, 2=abd, 3=state_cls
// ---------------------------------------------------------------------------
template<int HEAD>
__global__ __launch_bounds__(256) void gemm_head_kernel(
    const float* __restrict__ W1, const float* __restrict__ b1,
    const float* __restrict__ w2,
    const float* __restrict__ fct, const float* __restrict__ tgt,
    const float* __restrict__ tside, const float* __restrict__ cls,
    float* __restrict__ score, int K)
{
    __shared__ float As[16][68];   // [kk][row]
    __shared__ float Bs[16][68];   // [kk][col]
    const int tid = threadIdx.x;
    const int tx = tid & 15, ty = tid >> 4;
    const int m0 = blockIdx.x * 64;
    const int n0 = blockIdx.y * 64;

    // per-thread A staging assignment: row = tid/4, k-quad = (tid%4)*4
    const int arow = tid >> 2;
    const int kk0  = (tid & 3) * 4;
    const int r = m0 + arow;
    const float* p0; const float* p1;
    if (HEAD == 0) {            // x = [fct[b,f], tgt[b,t]], r = b*48 + t*12 + f
        int b = r / TNF_, q = r % TNF_;
        int t = q / NF_, f = q % NF_;
        p0 = fct + (size_t)(b*NF_ + f) * H_;
        p1 = tgt + (size_t)(b*T_ + t) * H_;
    } else if (HEAD == 1) {     // x = [fct[b,i1], fct[b,i2]], triu(12,1) order
        int b = r / NP_, p = r % NP_;
        int i = 0, rem = p, cnt = NF_ - 1;
        while (rem >= cnt) { rem -= cnt; --cnt; ++i; }
        int j = i + 1 + rem;
        p0 = fct + (size_t)(b*NF_ + i) * H_;
        p1 = fct + (size_t)(b*NF_ + j) * H_;
    } else if (HEAD == 2) {     // x = [tside[b], fct[b,f]]
        int b = r / NF_, f = r % NF_;
        p0 = tside + (size_t)b * H_;
        p1 = fct + (size_t)(b*NF_ + f) * H_;
    } else {                    // x = cls[b] (K = H)
        p0 = cls + (size_t)r * H_;
        p1 = p0;
    }

    const int bkk = tid >> 4;          // 0..15
    const int bc0 = (tid & 15) * 4;    // 0..60

    float acc[4][4] = {{0.f}};

    for (int k0 = 0; k0 < K; k0 += 16) {
        __syncthreads();
        // stage A (gathered): float4 along k, transposed scatter into As
        int g = k0 + kk0;
        const float* srcA = (g < H_) ? (p0 + g) : (p1 + (g - H_));
        float4 av = *(const float4*)srcA;
        As[kk0 + 0][arow] = av.x;
        As[kk0 + 1][arow] = av.y;
        As[kk0 + 2][arow] = av.z;
        As[kk0 + 3][arow] = av.w;
        // stage B: W1 row-major (K, 1024)
        float4 bv = *(const float4*)&W1[(size_t)(k0 + bkk) * H_ + n0 + bc0];
        *(float4*)&Bs[bkk][bc0] = bv;
        __syncthreads();

        #pragma unroll
        for (int kk = 0; kk < 16; ++kk) {
            float4 a4 = *(const float4*)&As[kk][ty * 4];
            float4 b4 = *(const float4*)&Bs[kk][tx * 4];
            float a[4] = {a4.x, a4.y, a4.z, a4.w};
            float bb[4] = {b4.x, b4.y, b4.z, b4.w};
            #pragma unroll
            for (int i = 0; i < 4; ++i)
                #pragma unroll
                for (int j = 0; j < 4; ++j)
                    acc[i][j] = fmaf(a[i], bb[j], acc[i][j]);
        }
    }

    // epilogue: + b1, relu, * w2, reduce over this block's 64 n-columns
    float bb1[4], ww2[4];
    #pragma unroll
    for (int j = 0; j < 4; ++j) {
        bb1[j] = b1[n0 + tx*4 + j];
        ww2[j] = w2[n0 + tx*4 + j];
    }
    #pragma unroll
    for (int i = 0; i < 4; ++i) {
        float part = 0.f;
        #pragma unroll
        for (int j = 0; j < 4; ++j) {
            float h = acc[i][j] + bb1[j];
            h = fmaxf(h, 0.f);
            part = fmaf(h, ww2[j], part);
        }
        // reduce across tx (lanes sharing ty live in one wave, tx = low 4 bits)
        #pragma unroll
        for (int msk = 1; msk < 16; msk <<= 1)
            part += __shfl_xor(part, msk);
        if (tx == 0)
            atomicAdd(&score[m0 + ty*4 + i], part);
    }
}

// ---------------------------------------------------------------------------
// Finalize: sigmoids, masked max/mean, lambda blend, 78-way softmax, output
// ---------------------------------------------------------------------------
__global__ __launch_bounds__(128) void finalize_kernel(
    const float* __restrict__ s_sent, const float* __restrict__ s_step,
    const float* __restrict__ s_abd, const float* __restrict__ s_cls,
    const float* __restrict__ mask, const float* __restrict__ lam,
    const float* __restrict__ sent_b2, const float* __restrict__ step_b2,
    const float* __restrict__ state_b2, const float* __restrict__ abd_b2,
    float* __restrict__ out)
{
    int b = blockIdx.x;
    int tid = threadIdx.x;
    __shared__ float fs[TNF_];
    __shared__ float sc[NP_ + NF_];
    __shared__ float mpf[NF_];
    __shared__ float smax, ssum;

    if (tid < TNF_) {
        float v = 1.f / (1.f + expf(-(s_sent[b*TNF_ + tid] + sent_b2[0])));
        fs[tid] = v;
        out[(size_t)b*OUTC_ + 1 + tid] = v;
    }
    if (tid < NP_)
        sc[tid] = s_step[b*NP_ + tid] + step_b2[0];
    else if (tid < NP_ + NF_)
        sc[tid] = s_abd[b*NF_ + (tid - NP_)] + abd_b2[0];
    __syncthreads();

    // mat = fs.reshape(12,4) (literal row-major reshape of t-major vector)
    if (tid < NF_) {
        float m = -1e30f;
        for (int j = 0; j < T_; ++j)
            m = fmaxf(m, fs[tid*T_ + j] * mask[((size_t)b*NF_ + tid)*T_ + j]);
        mpf[tid] = m;
    }
    __syncthreads();

    if (tid == 0) {
        float sf = 0.f;
        for (int i = 0; i < NF_; ++i) sf += mpf[i];
        sf *= (1.f / NF_);
        float scls = 1.f / (1.f + expf(-(s_cls[b] + state_b2[0])));
        float l0 = lam[0], l1 = lam[1];
        float mx = fmaxf(l0, l1);
        float e0 = expf(l0 - mx), e1 = expf(l1 - mx);
        float w0 = e0 / (e0 + e1);
        out[(size_t)b*OUTC_] = w0 * sf + (1.f - w0) * scls;
        float m2 = -1e30f;
        for (int i = 0; i < NP_ + NF_; ++i) m2 = fmaxf(m2, sc[i]);
        smax = m2;
    }
    __syncthreads();
    if (tid < NP_ + NF_) sc[tid] = expf(sc[tid] - smax);
    __syncthreads();
    if (tid == 0) {
        float s2 = 0.f;
        for (int i = 0; i < NP_ + NF_; ++i) s2 += sc[i];
        ssum = s2;
    }
    __syncthreads();
    if (tid < NP_ + NF_)
        out[(size_t)b*OUTC_ + 1 + TNF_ + tid] = sc[tid] / ssum;
}

// ---------------------------------------------------------------------------
extern "C" void kernel_launch(void* const* d_in, const int* in_sizes, int n_in,
                              void* d_out, int out_size, void* d_ws, size_t ws_size,
                              hipStream_t stream)
{
    (void)in_sizes; (void)n_in; (void)out_size; (void)ws_size;
    const float* seq  = (const float*)d_in[0];
    const float* cls  = (const float*)d_in[1];
    const int*   toff = (const int*)d_in[2];
    const int*   foff = (const int*)d_in[3];
    const float* mask = (const float*)d_in[4];
    const float* sw1  = (const float*)d_in[5];
    const float* sb1  = (const float*)d_in[6];
    const float* sw2  = (const float*)d_in[7];
    const float* sb2  = (const float*)d_in[8];
    const float* pw1  = (const float*)d_in[9];
    const float* pb1  = (const float*)d_in[10];
    const float* pw2  = (const float*)d_in[11];
    const float* pb2  = (const float*)d_in[12];
    const float* cw1  = (const float*)d_in[13];
    const float* cb1  = (const float*)d_in[14];
    const float* cw2  = (const float*)d_in[15];
    const float* cb2  = (const float*)d_in[16];
    const float* aw1  = (const float*)d_in[17];
    const float* ab1  = (const float*)d_in[18];
    const float* aw2  = (const float*)d_in[19];
    const float* ab2  = (const float*)d_in[20];
    const float* lam  = (const float*)d_in[21];

    float* ws    = (float*)d_ws;
    float* tgt   = ws + OFF_TGT;
    float* fct   = ws + OFF_FCT;
    float* tsd   = ws + OFF_TSIDE;
    float* ssent = ws + OFF_SSENT;
    float* sstep = ws + OFF_SSTEP;
    float* sabd  = ws + OFF_SABD;
    float* scls  = ws + OFF_SCLS;

    seg_mean_kernel<<<B_*(T_ + NF_), 256, 0, stream>>>(seq, toff, foff, tgt, fct);
    tside_kernel<<<B_, 256, 0, stream>>>(tgt, tsd);
    hipMemsetAsync(ssent, 0, sizeof(float) * SCORE_TOTAL, stream);

    gemm_head_kernel<0><<<dim3(3072/64, 16), 256, 0, stream>>>(
        sw1, sb1, sw2, fct, tgt, tsd, cls, ssent, 2*H_);
    gemm_head_kernel<1><<<dim3(4224/64, 16), 256, 0, stream>>>(
        pw1, pb1, pw2, fct, tgt, tsd, cls, sstep, 2*H_);
    gemm_head_kernel<2><<<dim3(768/64, 16), 256, 0, stream>>>(
        aw1, ab1, aw2, fct, tgt, tsd, cls, sabd, 2*H_);
    gemm_head_kernel<3><<<dim3(1, 16), 256, 0, stream>>>(
        cw1, cb1, cw2, fct, tgt, tsd, cls, scls, H_);

    finalize_kernel<<<B_, 128, 0, stream>>>(
        ssent, sstep, sabd, scls, mask, lam, sb2, pb2, cb2, ab2, (float*)d_out);
}

// Round 2
// 158.527 us; speedup vs baseline: 4.1326x; 4.1326x over previous
//
#include <hip/hip_runtime.h>
#include <hip/hip_bf16.h>

// Problem constants
#define B_    64
#define S_    512
#define H_    1024
#define HH_   (H_*H_)
#define T_    4
#define NF_   12
#define TNF_  48      // T*NF
#define NP_   66      // NF*(NF-1)/2
#define OUTC_ 127     // 1 + 48 + 66 + 12

// score counts
#define NSENT_ (B_*TNF_)   // 3072
#define NSTEP_ (B_*NP_)    // 4224
#define NABD_  (B_*NF_)    // 768
#define NCLS_  (B_)        // 64
#define NWAVES_ (NSENT_+NSTEP_+NABD_+NCLS_)  // 8128

// workspace layout (in floats)
#define OFF_TGT    0
#define OFF_FCT    (OFF_TGT   + B_*T_*H_)     // tgt: 262144
#define OFF_TSIDE  (OFF_FCT   + B_*NF_*H_)    // fct: 786432
#define OFF_GFSENT (OFF_TSIDE + B_*H_)
#define OFF_GS1    (OFF_GFSENT+ B_*NF_*H_)
#define OFF_GS2    (OFF_GS1   + B_*NF_*H_)
#define OFF_GAF    (OFF_GS2   + B_*NF_*H_)
#define OFF_GTSENT (OFF_GAF   + B_*NF_*H_)
#define OFF_GAT    (OFF_GTSENT+ B_*T_*H_)
#define OFF_GCLS   (OFF_GAT   + B_*H_)
#define OFF_SSENT  (OFF_GCLS  + B_*H_)
#define OFF_SSTEP  (OFF_SSENT + NSENT_)
#define OFF_SABD   (OFF_SSTEP + NSTEP_)
#define OFF_SCLS   (OFF_SABD  + NABD_)

// ---------------------------------------------------------------------------
// Segment means: one block per (b, segment). tgt (B,T,H), fct (B,NF,H)
// ---------------------------------------------------------------------------
__global__ __launch_bounds__(256) void seg_mean_kernel(
    const float* __restrict__ seq, const int* __restrict__ toffs,
    const int* __restrict__ foffs, float* __restrict__ tgt,
    float* __restrict__ fct)
{
    int blk = blockIdx.x;
    int b = blk >> 4;
    int k = blk & 15;
    int start, end;
    float* dst;
    if (k < T_) {
        start = toffs[(b*T_ + k)*2];
        end   = toffs[(b*T_ + k)*2 + 1];
        dst   = tgt + (size_t)(b*T_ + k) * H_;
    } else {
        int f = k - T_;
        start = foffs[(b*NF_ + f)*2];
        end   = foffs[(b*NF_ + f)*2 + 1];
        dst   = fct + (size_t)(b*NF_ + f) * H_;
    }
    int h0 = threadIdx.x * 4;
    const float* base = seq + ((size_t)b * S_ + start) * H_ + h0;
    float4 s = make_float4(0.f, 0.f, 0.f, 0.f);
    int n = end - start;
    for (int r = 0; r < n; ++r) {
        float4 v = *(const float4*)(base + (size_t)r * H_);
        s.x += v.x; s.y += v.y; s.z += v.z; s.w += v.w;
    }
    float inv = 1.f / (float)n;
    *(float4*)(dst + h0) = make_float4(s.x*inv, s.y*inv, s.z*inv, s.w*inv);
}

// tside = mean over T of tgt  -> (B, H)
__global__ __launch_bounds__(256) void tside_kernel(
    const float* __restrict__ tgt, float* __restrict__ tside)
{
    int b = blockIdx.x;
    int h0 = threadIdx.x * 4;
    float4 s = make_float4(0.f, 0.f, 0.f, 0.f);
    for (int t = 0; t < T_; ++t) {
        float4 v = *(const float4*)(tgt + (size_t)(b*T_ + t)*H_ + h0);
        s.x += v.x; s.y += v.y; s.z += v.z; s.w += v.w;
    }
    *(float4*)(tside + (size_t)b*H_ + h0) =
        make_float4(s.x*0.25f, s.y*0.25f, s.z*0.25f, s.w*0.25f);
}

// ---------------------------------------------------------------------------
// Merged GEMM: 7 jobs, all K=1024, N=1024, M in {768,768,768,768,256,64,64}.
// G[j] = A[j] (M x 1024, row-major) @ W[j] (1024 x 1024, row-major).
// 64x64 tile, BK=16, 256 threads, 4x4 microtile. grid = (54, 16).
// ---------------------------------------------------------------------------
__global__ __launch_bounds__(256) void gemm_merged_kernel(
    const float* __restrict__ fct, const float* __restrict__ tgt,
    const float* __restrict__ tsd, const float* __restrict__ cls,
    const float* __restrict__ sw1, const float* __restrict__ pw1,
    const float* __restrict__ aw1, const float* __restrict__ cw1,
    float* __restrict__ Gfsent, float* __restrict__ Gs1,
    float* __restrict__ Gs2, float* __restrict__ Gaf,
    float* __restrict__ Gtsent, float* __restrict__ Gat,
    float* __restrict__ Gcls)
{
    __shared__ float As[16][68];   // [kk][row]
    __shared__ float Bs[16][68];   // [kk][col]

    int bx = blockIdx.x;
    const float* A; const float* W; float* G; int mt;
    if (bx < 12)       { A = fct; W = sw1;       G = Gfsent; mt = bx; }
    else if (bx < 24)  { A = fct; W = pw1;       G = Gs1;    mt = bx - 12; }
    else if (bx < 36)  { A = fct; W = pw1 + HH_; G = Gs2;    mt = bx - 24; }
    else if (bx < 48)  { A = fct; W = aw1 + HH_; G = Gaf;    mt = bx - 36; }
    else if (bx < 52)  { A = tgt; W = sw1 + HH_; G = Gtsent; mt = bx - 48; }
    else if (bx == 52) { A = tsd; W = aw1;       G = Gat;    mt = 0; }
    else               { A = cls; W = cw1;       G = Gcls;   mt = 0; }

    const int tid = threadIdx.x;
    const int tx = tid & 15, ty = tid >> 4;
    const int m0 = mt * 64;
    const int n0 = blockIdx.y * 64;

    const int arow = tid >> 2;          // 0..63
    const int kq   = (tid & 3) * 4;     // 0,4,8,12
    const int bkk  = tid >> 4;          // 0..15
    const int bc0  = (tid & 15) * 4;    // 0..60

    const float* aptr = A + (size_t)(m0 + arow) * H_ + kq;
    const float* wptr = W + (size_t)bkk * H_ + n0 + bc0;

    float acc[4][4] = {{0.f}};

    for (int k0 = 0; k0 < H_; k0 += 16) {
        __syncthreads();
        float4 av = *(const float4*)(aptr + k0);
        As[kq + 0][arow] = av.x;
        As[kq + 1][arow] = av.y;
        As[kq + 2][arow] = av.z;
        As[kq + 3][arow] = av.w;
        *(float4*)&Bs[bkk][bc0] = *(const float4*)(wptr + (size_t)k0 * H_);
        __syncthreads();

        #pragma unroll
        for (int kk = 0; kk < 16; ++kk) {
            float4 a4 = *(const float4*)&As[kk][ty * 4];
            float4 b4 = *(const float4*)&Bs[kk][tx * 4];
            float a[4] = {a4.x, a4.y, a4.z, a4.w};
            float bb[4] = {b4.x, b4.y, b4.z, b4.w};
            #pragma unroll
            for (int i = 0; i < 4; ++i)
                #pragma unroll
                for (int j = 0; j < 4; ++j)
                    acc[i][j] = fmaf(a[i], bb[j], acc[i][j]);
        }
    }

    #pragma unroll
    for (int i = 0; i < 4; ++i) {
        float4 o = make_float4(acc[i][0], acc[i][1], acc[i][2], acc[i][3]);
        *(float4*)&G[(size_t)(m0 + ty*4 + i) * H_ + n0 + tx*4] = o;
    }
}

// ---------------------------------------------------------------------------
// Combine: one wave per score.  score = sum_n relu(U[n] (+V[n]) + b1[n])*w2[n]
// ---------------------------------------------------------------------------
__global__ __launch_bounds__(256) void combine_kernel(
    const float* __restrict__ Gfsent, const float* __restrict__ Gtsent,
    const float* __restrict__ Gs1, const float* __restrict__ Gs2,
    const float* __restrict__ Gat, const float* __restrict__ Gaf,
    const float* __restrict__ Gcls,
    const float* __restrict__ sb1, const float* __restrict__ sw2,
    const float* __restrict__ pb1, const float* __restrict__ pw2,
    const float* __restrict__ ab1, const float* __restrict__ aw2,
    const float* __restrict__ cb1, const float* __restrict__ cw2,
    float* __restrict__ ssent, float* __restrict__ sstep,
    float* __restrict__ sabd, float* __restrict__ scls)
{
    int w = blockIdx.x * 4 + (threadIdx.x >> 6);
    int lane = threadIdx.x & 63;
    if (w >= NWAVES_) return;

    const float *U, *V, *b1, *w2;
    float* outp;
    if (w < NSENT_) {
        int b = w / TNF_, q = w % TNF_;
        int t = q / NF_, f = q % NF_;
        U = Gfsent + (size_t)(b*NF_ + f) * H_;
        V = Gtsent + (size_t)(b*T_ + t) * H_;
        b1 = sb1; w2 = sw2; outp = ssent + w;
    } else if (w < NSENT_ + NSTEP_) {
        int s = w - NSENT_;
        int b = s / NP_, p = s % NP_;
        int i = 0, rem = p, cnt = NF_ - 1;
        while (rem >= cnt) { rem -= cnt; --cnt; ++i; }
        int j = i + 1 + rem;
        U = Gs1 + (size_t)(b*NF_ + i) * H_;
        V = Gs2 + (size_t)(b*NF_ + j) * H_;
        b1 = pb1; w2 = pw2; outp = sstep + s;
    } else if (w < NSENT_ + NSTEP_ + NABD_) {
        int s = w - NSENT_ - NSTEP_;
        int b = s / NF_, f = s % NF_;
        U = Gat + (size_t)b * H_;
        V = Gaf + (size_t)(b*NF_ + f) * H_;
        b1 = ab1; w2 = aw2; outp = sabd + s;
    } else {
        int b = w - NSENT_ - NSTEP_ - NABD_;
        U = Gcls + (size_t)b * H_;
        V = nullptr;
        b1 = cb1; w2 = cw2; outp = scls + b;
    }

    float acc = 0.f;
    #pragma unroll
    for (int e = 0; e < 4; ++e) {
        int n4 = (e * 64 + lane) * 4;
        float4 u = *(const float4*)(U + n4);
        if (V) {
            float4 v = *(const float4*)(V + n4);
            u.x += v.x; u.y += v.y; u.z += v.z; u.w += v.w;
        }
        float4 bb = *(const float4*)(b1 + n4);
        float4 ww = *(const float4*)(w2 + n4);
        acc = fmaf(fmaxf(u.x + bb.x, 0.f), ww.x, acc);
        acc = fmaf(fmaxf(u.y + bb.y, 0.f), ww.y, acc);
        acc = fmaf(fmaxf(u.z + bb.z, 0.f), ww.z, acc);
        acc = fmaf(fmaxf(u.w + bb.w, 0.f), ww.w, acc);
    }
    #pragma unroll
    for (int msk = 1; msk < 64; msk <<= 1)
        acc += __shfl_xor(acc, msk);
    if (lane == 0) *outp = acc;
}

// ---------------------------------------------------------------------------
// Finalize: sigmoids, masked max/mean, lambda blend, 78-way softmax, output
// ---------------------------------------------------------------------------
__global__ __launch_bounds__(128) void finalize_kernel(
    const float* __restrict__ s_sent, const float* __restrict__ s_step,
    const float* __restrict__ s_abd, const float* __restrict__ s_cls,
    const float* __restrict__ mask, const float* __restrict__ lam,
    const float* __restrict__ sent_b2, const float* __restrict__ step_b2,
    const float* __restrict__ state_b2, const float* __restrict__ abd_b2,
    float* __restrict__ out)
{
    int b = blockIdx.x;
    int tid = threadIdx.x;
    __shared__ float fs[TNF_];
    __shared__ float sc[NP_ + NF_];
    __shared__ float mpf[NF_];
    __shared__ float smax, ssum;

    if (tid < TNF_) {
        float v = 1.f / (1.f + expf(-(s_sent[b*TNF_ + tid] + sent_b2[0])));
        fs[tid] = v;
        out[(size_t)b*OUTC_ + 1 + tid] = v;
    }
    if (tid < NP_)
        sc[tid] = s_step[b*NP_ + tid] + step_b2[0];
    else if (tid < NP_ + NF_)
        sc[tid] = s_abd[b*NF_ + (tid - NP_)] + abd_b2[0];
    __syncthreads();

    // mat = fs.reshape(12,4) (literal row-major reshape of t-major vector)
    if (tid < NF_) {
        float m = -1e30f;
        for (int j = 0; j < T_; ++j)
            m = fmaxf(m, fs[tid*T_ + j] * mask[((size_t)b*NF_ + tid)*T_ + j]);
        mpf[tid] = m;
    }
    __syncthreads();

    if (tid == 0) {
        float sf = 0.f;
        for (int i = 0; i < NF_; ++i) sf += mpf[i];
        sf *= (1.f / NF_);
        float scls = 1.f / (1.f + expf(-(s_cls[b] + state_b2[0])));
        float l0 = lam[0], l1 = lam[1];
        float mx = fmaxf(l0, l1);
        float e0 = expf(l0 - mx), e1 = expf(l1 - mx);
        float w0 = e0 / (e0 + e1);
        out[(size_t)b*OUTC_] = w0 * sf + (1.f - w0) * scls;
        float m2 = -1e30f;
        for (int i = 0; i < NP_ + NF_; ++i) m2 = fmaxf(m2, sc[i]);
        smax = m2;
    }
    __syncthreads();
    if (tid < NP_ + NF_) sc[tid] = expf(sc[tid] - smax);
    __syncthreads();
    if (tid == 0) {
        float s2 = 0.f;
        for (int i = 0; i < NP_ + NF_; ++i) s2 += sc[i];
        ssum = s2;
    }
    __syncthreads();
    if (tid < NP_ + NF_)
        out[(size_t)b*OUTC_ + 1 + TNF_ + tid] = sc[tid] / ssum;
}

// ---------------------------------------------------------------------------
extern "C" void kernel_launch(void* const* d_in, const int* in_sizes, int n_in,
                              void* d_out, int out_size, void* d_ws, size_t ws_size,
                              hipStream_t stream)
{
    (void)in_sizes; (void)n_in; (void)out_size; (void)ws_size;
    const float* seq  = (const float*)d_in[0];
    const float* cls  = (const float*)d_in[1];
    const int*   toff = (const int*)d_in[2];
    const int*   foff = (const int*)d_in[3];
    const float* mask = (const float*)d_in[4];
    const float* sw1  = (const float*)d_in[5];
    const float* sb1  = (const float*)d_in[6];
    const float* sw2  = (const float*)d_in[7];
    const float* sb2  = (const float*)d_in[8];
    const float* pw1  = (const float*)d_in[9];
    const float* pb1  = (const float*)d_in[10];
    const float* pw2  = (const float*)d_in[11];
    const float* pb2  = (const float*)d_in[12];
    const float* cw1  = (const float*)d_in[13];
    const float* cb1  = (const float*)d_in[14];
    const float* cw2  = (const float*)d_in[15];
    const float* cb2  = (const float*)d_in[16];
    const float* aw1  = (const float*)d_in[17];
    const float* ab1  = (const float*)d_in[18];
    const float* aw2  = (const float*)d_in[19];
    const float* ab2  = (const float*)d_in[20];
    const float* lam  = (const float*)d_in[21];

    float* ws     = (float*)d_ws;
    float* tgt    = ws + OFF_TGT;
    float* fct    = ws + OFF_FCT;
    float* tsd    = ws + OFF_TSIDE;
    float* Gfsent = ws + OFF_GFSENT;
    float* Gs1    = ws + OFF_GS1;
    float* Gs2    = ws + OFF_GS2;
    float* Gaf    = ws + OFF_GAF;
    float* Gtsent = ws + OFF_GTSENT;
    float* Gat    = ws + OFF_GAT;
    float* Gcls   = ws + OFF_GCLS;
    float* ssent  = ws + OFF_SSENT;
    float* sstep  = ws + OFF_SSTEP;
    float* sabd   = ws + OFF_SABD;
    float* scls   = ws + OFF_SCLS;

    seg_mean_kernel<<<B_*(T_ + NF_), 256, 0, stream>>>(seq, toff, foff, tgt, fct);
    tside_kernel<<<B_, 256, 0, stream>>>(tgt, tsd);

    gemm_merged_kernel<<<dim3(54, 16), 256, 0, stream>>>(
        fct, tgt, tsd, cls, sw1, pw1, aw1, cw1,
        Gfsent, Gs1, Gs2, Gaf, Gtsent, Gat, Gcls);

    combine_kernel<<<(NWAVES_ + 3) / 4, 256, 0, stream>>>(
        Gfsent, Gtsent, Gs1, Gs2, Gat, Gaf, Gcls,
        sb1, sw2, pb1, pw2, ab1, aw2, cb1, cw2,
        ssent, sstep, sabd, scls);

    finalize_kernel<<<B_, 128, 0, stream>>>(
        ssent, sstep, sabd, scls, mask, lam, sb2, pb2, cb2, ab2, (float*)d_out);
}

// Round 3
// 65.653 us; speedup vs baseline: 9.9787x; 2.4146x over previous
//
#include <hip/hip_runtime.h>
#include <hip/hip_bf16.h>

// Problem constants
#define B_    64
#define S_    512
#define H_    1024
#define HH_   (H_*H_)
#define T_    4
#define NF_   12
#define TNF_  48      // T*NF
#define NP_   66      // NF*(NF-1)/2
#define OUTC_ 127     // 1 + 48 + 66 + 12

// score counts
#define NSENT_ (B_*TNF_)   // 3072
#define NSTEP_ (B_*NP_)    // 4224
#define NABD_  (B_*NF_)    // 768
#define NCLS_  (B_)        // 64
#define NWAVES_ (NSENT_+NSTEP_+NABD_+NCLS_)  // 8128

// A-buffer rows (bf16, row length 1024)
#define AROW_FCT   0      // 768 rows (b*12+f)
#define AROW_TGT   768    // 256 rows (b*4+t)
#define AROW_TSD   1024   // 64 rows
#define AROW_CLS   1088   // 64 rows
#define AROWS_     1152

// G rows (bf16, row length 1024): fsent, s1, s2, af, tsent, at, cls
#define GROW_FSENT 0
#define GROW_S1    768
#define GROW_S2    1536
#define GROW_AF    2304
#define GROW_TSENT 3072
#define GROW_AT    3328
#define GROW_CLS   3392
#define GROWS_     3456

typedef __bf16 bf16x8 __attribute__((ext_vector_type(8)));
typedef float  f32x4  __attribute__((ext_vector_type(4)));
typedef __attribute__((address_space(1))) const unsigned int gcu32;
typedef __attribute__((address_space(3))) unsigned int lu32;

__device__ __forceinline__ ushort f2bf(float x) {
    union { float f; unsigned u; } c; c.f = x;
    unsigned r = c.u + 0x7fffu + ((c.u >> 16) & 1u);
    return (ushort)(r >> 16);
}
__device__ __forceinline__ float bflo(unsigned u) {
    union { unsigned u; float f; } c; c.u = u << 16; return c.f;
}
__device__ __forceinline__ float bfhi(unsigned u) {
    union { unsigned u; float f; } c; c.u = u & 0xffff0000u; return c.f;
}

// ---------------------------------------------------------------------------
// Segment means -> bf16 A-buffer rows (+ fp32 tgt for tside)
// ---------------------------------------------------------------------------
__global__ __launch_bounds__(256) void seg_mean_kernel(
    const float* __restrict__ seq, const int* __restrict__ toffs,
    const int* __restrict__ foffs, float* __restrict__ tgt32,
    ushort* __restrict__ Abf)
{
    int blk = blockIdx.x;
    int b = blk >> 4;
    int k = blk & 15;
    int start, end, arow;
    float* dst32 = nullptr;
    if (k < T_) {
        start = toffs[(b*T_ + k)*2];
        end   = toffs[(b*T_ + k)*2 + 1];
        dst32 = tgt32 + (size_t)(b*T_ + k) * H_;
        arow  = AROW_TGT + b*T_ + k;
    } else {
        int f = k - T_;
        start = foffs[(b*NF_ + f)*2];
        end   = foffs[(b*NF_ + f)*2 + 1];
        arow  = AROW_FCT + b*NF_ + f;
    }
    int h0 = threadIdx.x * 4;
    const float* base = seq + ((size_t)b * S_ + start) * H_ + h0;
    float4 s = make_float4(0.f, 0.f, 0.f, 0.f);
    int n = end - start;
    for (int r = 0; r < n; ++r) {
        float4 v = *(const float4*)(base + (size_t)r * H_);
        s.x += v.x; s.y += v.y; s.z += v.z; s.w += v.w;
    }
    float inv = 1.f / (float)n;
    s.x *= inv; s.y *= inv; s.z *= inv; s.w *= inv;
    if (dst32) *(float4*)(dst32 + h0) = s;
    ushort4 q; q.x = f2bf(s.x); q.y = f2bf(s.y); q.z = f2bf(s.z); q.w = f2bf(s.w);
    *(ushort4*)(Abf + (size_t)arow * H_ + h0) = q;
}

// tside (mean of fp32 tgt) -> bf16 row; cls -> bf16 row
__global__ __launch_bounds__(256) void tside_cls_kernel(
    const float* __restrict__ tgt32, const float* __restrict__ cls,
    ushort* __restrict__ Abf)
{
    int b = blockIdx.x;
    int h0 = threadIdx.x * 4;
    float4 s = make_float4(0.f, 0.f, 0.f, 0.f);
    for (int t = 0; t < T_; ++t) {
        float4 v = *(const float4*)(tgt32 + (size_t)(b*T_ + t)*H_ + h0);
        s.x += v.x; s.y += v.y; s.z += v.z; s.w += v.w;
    }
    ushort4 q;
    q.x = f2bf(s.x*0.25f); q.y = f2bf(s.y*0.25f);
    q.z = f2bf(s.z*0.25f); q.w = f2bf(s.w*0.25f);
    *(ushort4*)(Abf + (size_t)(AROW_TSD + b) * H_ + h0) = q;
    float4 c = *(const float4*)(cls + (size_t)b * H_ + h0);
    ushort4 qc; qc.x = f2bf(c.x); qc.y = f2bf(c.y); qc.z = f2bf(c.z); qc.w = f2bf(c.w);
    *(ushort4*)(Abf + (size_t)(AROW_CLS + b) * H_ + h0) = qc;
}

// ---------------------------------------------------------------------------
// Transpose-cast: 7 x [1024][1024] fp32 (k-major) -> bf16 (n-major) Wt
// src order: 0 sw1-top, 1 pw1-top, 2 pw1-bot, 3 aw1-bot, 4 sw1-bot,
//            5 aw1-top, 6 cw1
// ---------------------------------------------------------------------------
__global__ __launch_bounds__(256) void transpose_cast_kernel(
    const float* __restrict__ sw1, const float* __restrict__ pw1,
    const float* __restrict__ aw1, const float* __restrict__ cw1,
    ushort* __restrict__ Wt)
{
    __shared__ float Tt[32][33];
    int z = blockIdx.z;
    const float* src;
    switch (z) {
        case 0: src = sw1; break;
        case 1: src = pw1; break;
        case 2: src = pw1 + HH_; break;
        case 3: src = aw1 + HH_; break;
        case 4: src = sw1 + HH_; break;
        case 5: src = aw1; break;
        default: src = cw1; break;
    }
    int k0 = blockIdx.x * 32;
    int n0 = blockIdx.y * 32;
    int tid = threadIdx.x;
    int ty = tid >> 3, tx = tid & 7;
    float4 v = *(const float4*)(src + (size_t)(k0 + ty) * H_ + n0 + tx*4);
    Tt[ty][tx*4 + 0] = v.x; Tt[ty][tx*4 + 1] = v.y;
    Tt[ty][tx*4 + 2] = v.z; Tt[ty][tx*4 + 3] = v.w;
    __syncthreads();
    int nx = ty, kx = tx;
    ushort4 q;
    q.x = f2bf(Tt[kx*4 + 0][nx]); q.y = f2bf(Tt[kx*4 + 1][nx]);
    q.z = f2bf(Tt[kx*4 + 2][nx]); q.w = f2bf(Tt[kx*4 + 3][nx]);
    *(ushort4*)(Wt + (size_t)z * HH_ + (size_t)(n0 + nx) * H_ + k0 + kx*4) = q;
}

// ---------------------------------------------------------------------------
// Merged bf16 MFMA GEMM: G = A @ W, 7 jobs, 64x64 tile, BK=32.
// 256 thr = 4 waves (2x2), each wave 32x32 = 2x2 frags of 16x16x32.
// grid (54, 16).
// ---------------------------------------------------------------------------
__global__ __launch_bounds__(256) void gemm_bf16_kernel(
    const ushort* __restrict__ Abf, const ushort* __restrict__ Wt,
    ushort* __restrict__ G)
{
    __shared__ __align__(16) ushort As[64*32];
    __shared__ __align__(16) ushort Bs[64*32];

    int bx = blockIdx.x;
    int arow_base, wsel, grow_base, mt;
    if (bx < 48)      { int j = bx / 12; mt = bx % 12; arow_base = AROW_FCT; wsel = j; grow_base = j * 768; }
    else if (bx < 52) { mt = bx - 48; arow_base = AROW_TGT; wsel = 4; grow_base = GROW_TSENT; }
    else if (bx == 52){ mt = 0; arow_base = AROW_TSD; wsel = 5; grow_base = GROW_AT; }
    else              { mt = 0; arow_base = AROW_CLS; wsel = 6; grow_base = GROW_CLS; }

    const int tid  = threadIdx.x;
    const int lane = tid & 63;
    const int w    = tid >> 6;        // 0..3
    const int wr   = w >> 1, wc = w & 1;
    const int m0   = mt * 64;
    const int n0   = blockIdx.y * 64;

    // staging: wave w covers rows 16w..16w+15 of the 64-row tile; 4 lanes/row
    const int srow   = lane >> 2;
    const int scol8  = (lane & 3) * 8;     // bf16 elems
    const ushort* gA = Abf + (size_t)(arow_base + m0 + w*16 + srow) * H_ + scol8;
    const ushort* gB = Wt + (size_t)wsel * HH_ + (size_t)(n0 + w*16 + srow) * H_ + scol8;
    ushort* ldsA = As + w * 512;     // wave-uniform base (16 rows * 32 elems)
    ushort* ldsB = Bs + w * 512;

    f32x4 acc00 = {0.f,0.f,0.f,0.f}, acc01 = {0.f,0.f,0.f,0.f};
    f32x4 acc10 = {0.f,0.f,0.f,0.f}, acc11 = {0.f,0.f,0.f,0.f};

    const int frow = lane & 15;
    const int fk   = (lane >> 4) * 8;
    const ushort* pa = As + (wr*32 + frow) * 32 + fk;
    const ushort* pb = Bs + (wc*32 + frow) * 32 + fk;

    for (int k0 = 0; k0 < H_; k0 += 32) {
        __syncthreads();
        __builtin_amdgcn_global_load_lds((gcu32*)(gA + k0), (lu32*)ldsA, 16, 0, 0);
        __builtin_amdgcn_global_load_lds((gcu32*)(gB + k0), (lu32*)ldsB, 16, 0, 0);
        __syncthreads();

        bf16x8 a0 = *(const bf16x8*)pa;
        bf16x8 a1 = *(const bf16x8*)(pa + 16*32);
        bf16x8 b0 = *(const bf16x8*)pb;
        bf16x8 b1 = *(const bf16x8*)(pb + 16*32);

        acc00 = __builtin_amdgcn_mfma_f32_16x16x32_bf16(a0, b0, acc00, 0, 0, 0);
        acc01 = __builtin_amdgcn_mfma_f32_16x16x32_bf16(a0, b1, acc01, 0, 0, 0);
        acc10 = __builtin_amdgcn_mfma_f32_16x16x32_bf16(a1, b0, acc10, 0, 0, 0);
        acc11 = __builtin_amdgcn_mfma_f32_16x16x32_bf16(a1, b1, acc11, 0, 0, 0);
    }

    // C/D layout: col = lane&15, row = (lane>>4)*4 + reg   [verified m89]
    const int r0 = (lane >> 4) * 4;
    const int c  = lane & 15;
    const size_t rowb = (size_t)(grow_base + m0 + wr*32);
    #pragma unroll
    for (int r = 0; r < 4; ++r) {
        G[(rowb + 0  + r0 + r) * H_ + n0 + wc*32 + 0  + c] = f2bf(acc00[r]);
        G[(rowb + 0  + r0 + r) * H_ + n0 + wc*32 + 16 + c] = f2bf(acc01[r]);
        G[(rowb + 16 + r0 + r) * H_ + n0 + wc*32 + 0  + c] = f2bf(acc10[r]);
        G[(rowb + 16 + r0 + r) * H_ + n0 + wc*32 + 16 + c] = f2bf(acc11[r]);
    }
}

// ---------------------------------------------------------------------------
// Combine: one wave per score. score = sum_n relu(U[n](+V[n])+b1[n])*w2[n]
// ---------------------------------------------------------------------------
__global__ __launch_bounds__(256) void combine_kernel(
    const ushort* __restrict__ G,
    const float* __restrict__ sb1, const float* __restrict__ sw2,
    const float* __restrict__ pb1, const float* __restrict__ pw2,
    const float* __restrict__ ab1, const float* __restrict__ aw2,
    const float* __restrict__ cb1, const float* __restrict__ cw2,
    float* __restrict__ ssent, float* __restrict__ sstep,
    float* __restrict__ sabd, float* __restrict__ scls)
{
    int wv = blockIdx.x * 4 + (threadIdx.x >> 6);
    int lane = threadIdx.x & 63;
    if (wv >= NWAVES_) return;

    const ushort *U, *V;
    const float *b1, *w2;
    float* outp;
    if (wv < NSENT_) {
        int b = wv / TNF_, q = wv % TNF_;
        int t = q / NF_, f = q % NF_;
        U = G + (size_t)(GROW_FSENT + b*NF_ + f) * H_;
        V = G + (size_t)(GROW_TSENT + b*T_ + t) * H_;
        b1 = sb1; w2 = sw2; outp = ssent + wv;
    } else if (wv < NSENT_ + NSTEP_) {
        int s = wv - NSENT_;
        int b = s / NP_, p = s % NP_;
        int i = 0, rem = p, cnt = NF_ - 1;
        while (rem >= cnt) { rem -= cnt; --cnt; ++i; }
        int j = i + 1 + rem;
        U = G + (size_t)(GROW_S1 + b*NF_ + i) * H_;
        V = G + (size_t)(GROW_S2 + b*NF_ + j) * H_;
        b1 = pb1; w2 = pw2; outp = sstep + s;
    } else if (wv < NSENT_ + NSTEP_ + NABD_) {
        int s = wv - NSENT_ - NSTEP_;
        int b = s / NF_, f = s % NF_;
        U = G + (size_t)(GROW_AT + b) * H_;
        V = G + (size_t)(GROW_AF + b*NF_ + f) * H_;
        b1 = ab1; w2 = aw2; outp = sabd + s;
    } else {
        int b = wv - NSENT_ - NSTEP_ - NABD_;
        U = G + (size_t)(GROW_CLS + b) * H_;
        V = nullptr;
        b1 = cb1; w2 = cw2; outp = scls + b;
    }

    float acc = 0.f;
    #pragma unroll
    for (int h = 0; h < 2; ++h) {
        int nb = h * 512 + lane * 8;
        uint4 uu = *(const uint4*)(U + nb);
        float us[8] = { bflo(uu.x), bfhi(uu.x), bflo(uu.y), bfhi(uu.y),
                        bflo(uu.z), bfhi(uu.z), bflo(uu.w), bfhi(uu.w) };
        if (V) {
            uint4 vv = *(const uint4*)(V + nb);
            us[0] += bflo(vv.x); us[1] += bfhi(vv.x);
            us[2] += bflo(vv.y); us[3] += bfhi(vv.y);
            us[4] += bflo(vv.z); us[5] += bfhi(vv.z);
            us[6] += bflo(vv.w); us[7] += bfhi(vv.w);
        }
        float4 bA = *(const float4*)(b1 + nb);
        float4 bB = *(const float4*)(b1 + nb + 4);
        float4 wA = *(const float4*)(w2 + nb);
        float4 wB = *(const float4*)(w2 + nb + 4);
        acc = fmaf(fmaxf(us[0] + bA.x, 0.f), wA.x, acc);
        acc = fmaf(fmaxf(us[1] + bA.y, 0.f), wA.y, acc);
        acc = fmaf(fmaxf(us[2] + bA.z, 0.f), wA.z, acc);
        acc = fmaf(fmaxf(us[3] + bA.w, 0.f), wA.w, acc);
        acc = fmaf(fmaxf(us[4] + bB.x, 0.f), wB.x, acc);
        acc = fmaf(fmaxf(us[5] + bB.y, 0.f), wB.y, acc);
        acc = fmaf(fmaxf(us[6] + bB.z, 0.f), wB.z, acc);
        acc = fmaf(fmaxf(us[7] + bB.w, 0.f), wB.w, acc);
    }
    #pragma unroll
    for (int msk = 1; msk < 64; msk <<= 1)
        acc += __shfl_xor(acc, msk);
    if (lane == 0) *outp = acc;
}

// ---------------------------------------------------------------------------
// Finalize: sigmoids, masked max/mean, lambda blend, 78-way softmax, output
// ---------------------------------------------------------------------------
__global__ __launch_bounds__(128) void finalize_kernel(
    const float* __restrict__ s_sent, const float* __restrict__ s_step,
    const float* __restrict__ s_abd, const float* __restrict__ s_cls,
    const float* __restrict__ mask, const float* __restrict__ lam,
    const float* __restrict__ sent_b2, const float* __restrict__ step_b2,
    const float* __restrict__ state_b2, const float* __restrict__ abd_b2,
    float* __restrict__ out)
{
    int b = blockIdx.x;
    int tid = threadIdx.x;
    __shared__ float fs[TNF_];
    __shared__ float sc[NP_ + NF_];
    __shared__ float mpf[NF_];
    __shared__ float smax, ssum;

    if (tid < TNF_) {
        float v = 1.f / (1.f + expf(-(s_sent[b*TNF_ + tid] + sent_b2[0])));
        fs[tid] = v;
        out[(size_t)b*OUTC_ + 1 + tid] = v;
    }
    if (tid < NP_)
        sc[tid] = s_step[b*NP_ + tid] + step_b2[0];
    else if (tid < NP_ + NF_)
        sc[tid] = s_abd[b*NF_ + (tid - NP_)] + abd_b2[0];
    __syncthreads();

    if (tid < NF_) {
        float m = -1e30f;
        for (int j = 0; j < T_; ++j)
            m = fmaxf(m, fs[tid*T_ + j] * mask[((size_t)b*NF_ + tid)*T_ + j]);
        mpf[tid] = m;
    }
    __syncthreads();

    if (tid == 0) {
        float sf = 0.f;
        for (int i = 0; i < NF_; ++i) sf += mpf[i];
        sf *= (1.f / NF_);
        float scls2 = 1.f / (1.f + expf(-(s_cls[b] + state_b2[0])));
        float l0 = lam[0], l1 = lam[1];
        float mx = fmaxf(l0, l1);
        float e0 = expf(l0 - mx), e1 = expf(l1 - mx);
        float w0 = e0 / (e0 + e1);
        out[(size_t)b*OUTC_] = w0 * sf + (1.f - w0) * scls2;
        float m2 = -1e30f;
        for (int i = 0; i < NP_ + NF_; ++i) m2 = fmaxf(m2, sc[i]);
        smax = m2;
    }
    __syncthreads();
    if (tid < NP_ + NF_) sc[tid] = expf(sc[tid] - smax);
    __syncthreads();
    if (tid == 0) {
        float s2 = 0.f;
        for (int i = 0; i < NP_ + NF_; ++i) s2 += sc[i];
        ssum = s2;
    }
    __syncthreads();
    if (tid < NP_ + NF_)
        out[(size_t)b*OUTC_ + 1 + TNF_ + tid] = sc[tid] / ssum;
}

// ---------------------------------------------------------------------------
extern "C" void kernel_launch(void* const* d_in, const int* in_sizes, int n_in,
                              void* d_out, int out_size, void* d_ws, size_t ws_size,
                              hipStream_t stream)
{
    (void)in_sizes; (void)n_in; (void)out_size; (void)ws_size;
    const float* seq  = (const float*)d_in[0];
    const float* cls  = (const float*)d_in[1];
    const int*   toff = (const int*)d_in[2];
    const int*   foff = (const int*)d_in[3];
    const float* mask = (const float*)d_in[4];
    const float* sw1  = (const float*)d_in[5];
    const float* sb1  = (const float*)d_in[6];
    const float* sw2  = (const float*)d_in[7];
    const float* sb2  = (const float*)d_in[8];
    const float* pw1  = (const float*)d_in[9];
    const float* pb1  = (const float*)d_in[10];
    const float* pw2  = (const float*)d_in[11];
    const float* pb2  = (const float*)d_in[12];
    const float* cw1  = (const float*)d_in[13];
    const float* cb1  = (const float*)d_in[14];
    const float* cw2  = (const float*)d_in[15];
    const float* cb2  = (const float*)d_in[16];
    const float* aw1  = (const float*)d_in[17];
    const float* ab1  = (const float*)d_in[18];
    const float* aw2  = (const float*)d_in[19];
    const float* ab2  = (const float*)d_in[20];
    const float* lam  = (const float*)d_in[21];

    char* wsb = (char*)d_ws;
    float*  tgt32 = (float*)wsb;                              // 1 MB
    float*  ssent = (float*)(wsb + (1u<<20));                 // 8128 floats
    float*  sstep = ssent + NSENT_;
    float*  sabd  = sstep + NSTEP_;
    float*  scls  = sabd + NABD_;
    ushort* Abf   = (ushort*)(wsb + (1u<<20) + 32768);        // 2.36 MB
    ushort* Wt    = Abf + (size_t)AROWS_ * H_;                // 14.68 MB
    ushort* G     = Wt + (size_t)7 * HH_;                     // 7.08 MB

    seg_mean_kernel<<<B_*(T_ + NF_), 256, 0, stream>>>(seq, toff, foff, tgt32, Abf);
    tside_cls_kernel<<<B_, 256, 0, stream>>>(tgt32, cls, Abf);
    transpose_cast_kernel<<<dim3(32, 32, 7), 256, 0, stream>>>(sw1, pw1, aw1, cw1, Wt);

    gemm_bf16_kernel<<<dim3(54, 16), 256, 0, stream>>>(Abf, Wt, G);

    combine_kernel<<<(NWAVES_ + 3) / 4, 256, 0, stream>>>(
        G, sb1, sw2, pb1, pw2, ab1, aw2, cb1, cw2,
        ssent, sstep, sabd, scls);

    finalize_kernel<<<B_, 128, 0, stream>>>(
        ssent, sstep, sabd, scls, mask, lam, sb2, pb2, cb2, ab2, (float*)d_out);
}

// Round 4
// 65.253 us; speedup vs baseline: 10.0398x; 1.0061x over previous
//
#include <hip/hip_runtime.h>
#include <hip/hip_bf16.h>

// Problem constants
#define B_    64
#define S_    512
#define H_    1024
#define HH_   (H_*H_)
#define T_    4
#define NF_   12
#define TNF_  48      // T*NF
#define NP_   66      // NF*(NF-1)/2
#define OUTC_ 127     // 1 + 48 + 66 + 12

// score counts
#define NSENT_ (B_*TNF_)   // 3072
#define NSTEP_ (B_*NP_)    // 4224
#define NABD_  (B_*NF_)    // 768
#define NCLS_  (B_)        // 64
#define NWAVES_ (NSENT_+NSTEP_+NABD_+NCLS_)  // 8128

// A-buffer rows (bf16, row length 1024)
#define AROW_FCT   0      // 768 rows (b*12+f)
#define AROW_TGT   768    // 256 rows (b*4+t)
#define AROW_TSD   1024   // 64 rows
#define AROW_CLS   1088   // 64 rows
#define AROWS_     1152

// G rows (bf16, row length 1024): fsent, s1, s2, af, tsent, at, cls
#define GROW_FSENT 0
#define GROW_S1    768
#define GROW_S2    1536
#define GROW_AF    2304
#define GROW_TSENT 3072
#define GROW_AT    3328
#define GROW_CLS   3392
#define GROWS_     3456

typedef __bf16 bf16x8 __attribute__((ext_vector_type(8)));
typedef float  f32x4  __attribute__((ext_vector_type(4)));
typedef __attribute__((address_space(1))) const unsigned int gcu32;
typedef __attribute__((address_space(3))) unsigned int lu32;

__device__ __forceinline__ ushort f2bf(float x) {
    union { float f; unsigned u; } c; c.f = x;
    unsigned r = c.u + 0x7fffu + ((c.u >> 16) & 1u);
    return (ushort)(r >> 16);
}
__device__ __forceinline__ float bflo(unsigned u) {
    union { unsigned u; float f; } c; c.u = u << 16; return c.f;
}
__device__ __forceinline__ float bfhi(unsigned u) {
    union { unsigned u; float f; } c; c.u = u & 0xffff0000u; return c.f;
}

// ---------------------------------------------------------------------------
// Prep (merged): blocks [0,1024) segment means -> bf16 A rows (+fp32 tgt),
//                blocks [1024,1088) cls cast, blocks [1088,8256) W1 transpose.
// ---------------------------------------------------------------------------
__global__ __launch_bounds__(256) void prep_kernel(
    const float* __restrict__ seq, const int* __restrict__ toffs,
    const int* __restrict__ foffs, const float* __restrict__ cls,
    const float* __restrict__ sw1, const float* __restrict__ pw1,
    const float* __restrict__ aw1, const float* __restrict__ cw1,
    float* __restrict__ tgt32, ushort* __restrict__ Abf,
    ushort* __restrict__ Wt)
{
    int blk = blockIdx.x;
    int tid = threadIdx.x;

    if (blk < 1024) {
        // ---- segment mean ----
        int b = blk >> 4;
        int k = blk & 15;
        int start, end, arow;
        float* dst32 = nullptr;
        if (k < T_) {
            start = toffs[(b*T_ + k)*2];
            end   = toffs[(b*T_ + k)*2 + 1];
            dst32 = tgt32 + (size_t)(b*T_ + k) * H_;
            arow  = AROW_TGT + b*T_ + k;
        } else {
            int f = k - T_;
            start = foffs[(b*NF_ + f)*2];
            end   = foffs[(b*NF_ + f)*2 + 1];
            arow  = AROW_FCT + b*NF_ + f;
        }
        int h0 = tid * 4;
        const float* base = seq + ((size_t)b * S_ + start) * H_ + h0;
        float4 s = make_float4(0.f, 0.f, 0.f, 0.f);
        int n = end - start;
        #pragma unroll 4
        for (int r = 0; r < n; ++r) {
            float4 v = *(const float4*)(base + (size_t)r * H_);
            s.x += v.x; s.y += v.y; s.z += v.z; s.w += v.w;
        }
        float inv = 1.f / (float)n;
        s.x *= inv; s.y *= inv; s.z *= inv; s.w *= inv;
        if (dst32) *(float4*)(dst32 + h0) = s;
        ushort4 q; q.x = f2bf(s.x); q.y = f2bf(s.y); q.z = f2bf(s.z); q.w = f2bf(s.w);
        *(ushort4*)(Abf + (size_t)arow * H_ + h0) = q;
    } else if (blk < 1088) {
        // ---- cls cast ----
        int b = blk - 1024;
        int h0 = tid * 4;
        float4 c = *(const float4*)(cls + (size_t)b * H_ + h0);
        ushort4 qc; qc.x = f2bf(c.x); qc.y = f2bf(c.y); qc.z = f2bf(c.z); qc.w = f2bf(c.w);
        *(ushort4*)(Abf + (size_t)(AROW_CLS + b) * H_ + h0) = qc;
    } else {
        // ---- transpose-cast 32x32 tile of one of 7 fp32 [1024][1024] blocks
        // src order: 0 sw1-top, 1 pw1-top, 2 pw1-bot, 3 aw1-bot, 4 sw1-bot,
        //            5 aw1-top, 6 cw1
        __shared__ float Tt[32][33];
        int idx2 = blk - 1088;
        int z = idx2 >> 10;
        int rem = idx2 & 1023;
        int k0 = (rem >> 5) * 32;
        int n0 = (rem & 31) * 32;
        const float* src;
        switch (z) {
            case 0: src = sw1; break;
            case 1: src = pw1; break;
            case 2: src = pw1 + HH_; break;
            case 3: src = aw1 + HH_; break;
            case 4: src = sw1 + HH_; break;
            case 5: src = aw1; break;
            default: src = cw1; break;
        }
        int ty = tid >> 3, tx = tid & 7;
        float4 v = *(const float4*)(src + (size_t)(k0 + ty) * H_ + n0 + tx*4);
        Tt[ty][tx*4 + 0] = v.x; Tt[ty][tx*4 + 1] = v.y;
        Tt[ty][tx*4 + 2] = v.z; Tt[ty][tx*4 + 3] = v.w;
        __syncthreads();
        int nx = ty, kx = tx;
        ushort4 q;
        q.x = f2bf(Tt[kx*4 + 0][nx]); q.y = f2bf(Tt[kx*4 + 1][nx]);
        q.z = f2bf(Tt[kx*4 + 2][nx]); q.w = f2bf(Tt[kx*4 + 3][nx]);
        *(ushort4*)(Wt + (size_t)z * HH_ + (size_t)(n0 + nx) * H_ + k0 + kx*4) = q;
    }
}

// tside (mean of fp32 tgt) -> bf16 row
__global__ __launch_bounds__(256) void tside_kernel(
    const float* __restrict__ tgt32, ushort* __restrict__ Abf)
{
    int b = blockIdx.x;
    int h0 = threadIdx.x * 4;
    float4 s = make_float4(0.f, 0.f, 0.f, 0.f);
    for (int t = 0; t < T_; ++t) {
        float4 v = *(const float4*)(tgt32 + (size_t)(b*T_ + t)*H_ + h0);
        s.x += v.x; s.y += v.y; s.z += v.z; s.w += v.w;
    }
    ushort4 q;
    q.x = f2bf(s.x*0.25f); q.y = f2bf(s.y*0.25f);
    q.z = f2bf(s.z*0.25f); q.w = f2bf(s.w*0.25f);
    *(ushort4*)(Abf + (size_t)(AROW_TSD + b) * H_ + h0) = q;
}

// ---------------------------------------------------------------------------
// Merged bf16 MFMA GEMM: G = A @ W, 7 jobs. 64x128 tile, BK=32, dbuf LDS,
// one barrier per K-step. 256 thr = 4 waves (2x2), wave tile 32x64 =
// 2x4 frags of 16x16x32. grid (54, 8).
// ---------------------------------------------------------------------------
__global__ __launch_bounds__(256) void gemm_bf16_kernel(
    const ushort* __restrict__ Abf, const ushort* __restrict__ Wt,
    ushort* __restrict__ G)
{
    // double-buffered: A 2x 64x32, B 2x 128x32 (bf16)
    __shared__ __align__(16) ushort As[2][64*32];
    __shared__ __align__(16) ushort Bs[2][128*32];

    int bx = blockIdx.x;
    int arow_base, wsel, grow_base, mt;
    if (bx < 48)      { int j = bx / 12; mt = bx % 12; arow_base = AROW_FCT; wsel = j; grow_base = j * 768; }
    else if (bx < 52) { mt = bx - 48; arow_base = AROW_TGT; wsel = 4; grow_base = GROW_TSENT; }
    else if (bx == 52){ mt = 0; arow_base = AROW_TSD; wsel = 5; grow_base = GROW_AT; }
    else              { mt = 0; arow_base = AROW_CLS; wsel = 6; grow_base = GROW_CLS; }

    const int tid  = threadIdx.x;
    const int lane = tid & 63;
    const int w    = tid >> 6;        // 0..3
    const int wr   = w >> 1, wc = w & 1;
    const int m0   = mt * 64;
    const int n0   = blockIdx.y * 128;

    // staging lanes: 4 lanes per row, 8 bf16 (16B) per lane
    const int srow  = lane >> 2;
    const int scol8 = (lane & 3) * 8;
    // A: wave w stages rows 16w..16w+15 of the 64-row tile
    const ushort* gA  = Abf + (size_t)(arow_base + m0 + w*16 + srow) * H_ + scol8;
    // B: wave w stages n-rows 32w..32w+31 (two 16-row halves)
    const ushort* gB0 = Wt + (size_t)wsel * HH_ + (size_t)(n0 + w*32 + srow) * H_ + scol8;
    const ushort* gB1 = gB0 + (size_t)16 * H_;

    f32x4 acc00 = {0,0,0,0}, acc01 = {0,0,0,0}, acc02 = {0,0,0,0}, acc03 = {0,0,0,0};
    f32x4 acc10 = {0,0,0,0}, acc11 = {0,0,0,0}, acc12 = {0,0,0,0}, acc13 = {0,0,0,0};

    const int frow = lane & 15;
    const int fk   = (lane >> 4) * 8;

    #define STAGE(buf, kk) do {                                                   \
        __builtin_amdgcn_global_load_lds((gcu32*)(gA  + (kk)), (lu32*)(As[buf] + w*512), 16, 0, 0);          \
        __builtin_amdgcn_global_load_lds((gcu32*)(gB0 + (kk)), (lu32*)(Bs[buf] + w*1024), 16, 0, 0);         \
        __builtin_amdgcn_global_load_lds((gcu32*)(gB1 + (kk)), (lu32*)(Bs[buf] + w*1024 + 512), 16, 0, 0);   \
    } while (0)

    STAGE(0, 0);
    __syncthreads();   // drains vmcnt before barrier (compiler-inserted)

    #pragma unroll 1
    for (int t = 0; t < 32; ++t) {
        const int cur = t & 1;
        if (t < 31) STAGE(cur ^ 1, (t + 1) * 32);

        const ushort* pa = As[cur] + (wr*32 + frow) * 32 + fk;
        const ushort* pb = Bs[cur] + (wc*64 + frow) * 32 + fk;
        bf16x8 a0 = *(const bf16x8*)pa;
        bf16x8 a1 = *(const bf16x8*)(pa + 512);
        bf16x8 b0 = *(const bf16x8*)pb;
        bf16x8 b1 = *(const bf16x8*)(pb + 512);
        bf16x8 b2 = *(const bf16x8*)(pb + 1024);
        bf16x8 b3 = *(const bf16x8*)(pb + 1536);

        acc00 = __builtin_amdgcn_mfma_f32_16x16x32_bf16(a0, b0, acc00, 0, 0, 0);
        acc01 = __builtin_amdgcn_mfma_f32_16x16x32_bf16(a0, b1, acc01, 0, 0, 0);
        acc02 = __builtin_amdgcn_mfma_f32_16x16x32_bf16(a0, b2, acc02, 0, 0, 0);
        acc03 = __builtin_amdgcn_mfma_f32_16x16x32_bf16(a0, b3, acc03, 0, 0, 0);
        acc10 = __builtin_amdgcn_mfma_f32_16x16x32_bf16(a1, b0, acc10, 0, 0, 0);
        acc11 = __builtin_amdgcn_mfma_f32_16x16x32_bf16(a1, b1, acc11, 0, 0, 0);
        acc12 = __builtin_amdgcn_mfma_f32_16x16x32_bf16(a1, b2, acc12, 0, 0, 0);
        acc13 = __builtin_amdgcn_mfma_f32_16x16x32_bf16(a1, b3, acc13, 0, 0, 0);

        if (t < 31) __syncthreads();   // vmcnt drained here; next buf ready
    }
    #undef STAGE

    // C/D layout: col = lane&15, row = (lane>>4)*4 + reg   [verified m89]
    const int r0 = (lane >> 4) * 4;
    const int c  = lane & 15;
    const size_t rowb = (size_t)(grow_base + m0 + wr*32);
    const size_t colb = (size_t)(n0 + wc*64);
    #pragma unroll
    for (int r = 0; r < 4; ++r) {
        size_t ra = (rowb + r0 + r) * H_ + colb;
        size_t rb = (rowb + 16 + r0 + r) * H_ + colb;
        G[ra + 0  + c] = f2bf(acc00[r]);
        G[ra + 16 + c] = f2bf(acc01[r]);
        G[ra + 32 + c] = f2bf(acc02[r]);
        G[ra + 48 + c] = f2bf(acc03[r]);
        G[rb + 0  + c] = f2bf(acc10[r]);
        G[rb + 16 + c] = f2bf(acc11[r]);
        G[rb + 32 + c] = f2bf(acc12[r]);
        G[rb + 48 + c] = f2bf(acc13[r]);
    }
}

// ---------------------------------------------------------------------------
// Combine: one wave per score. score = sum_n relu(U[n](+V[n])+b1[n])*w2[n]
// ---------------------------------------------------------------------------
__global__ __launch_bounds__(256) void combine_kernel(
    const ushort* __restrict__ G,
    const float* __restrict__ sb1, const float* __restrict__ sw2,
    const float* __restrict__ pb1, const float* __restrict__ pw2,
    const float* __restrict__ ab1, const float* __restrict__ aw2,
    const float* __restrict__ cb1, const float* __restrict__ cw2,
    float* __restrict__ ssent, float* __restrict__ sstep,
    float* __restrict__ sabd, float* __restrict__ scls)
{
    int wv = blockIdx.x * 4 + (threadIdx.x >> 6);
    int lane = threadIdx.x & 63;
    if (wv >= NWAVES_) return;

    const ushort *U, *V;
    const float *b1, *w2;
    float* outp;
    if (wv < NSENT_) {
        int b = wv / TNF_, q = wv % TNF_;
        int t = q / NF_, f = q % NF_;
        U = G + (size_t)(GROW_FSENT + b*NF_ + f) * H_;
        V = G + (size_t)(GROW_TSENT + b*T_ + t) * H_;
        b1 = sb1; w2 = sw2; outp = ssent + wv;
    } else if (wv < NSENT_ + NSTEP_) {
        int s = wv - NSENT_;
        int b = s / NP_, p = s % NP_;
        int i = 0, rem = p, cnt = NF_ - 1;
        while (rem >= cnt) { rem -= cnt; --cnt; ++i; }
        int j = i + 1 + rem;
        U = G + (size_t)(GROW_S1 + b*NF_ + i) * H_;
        V = G + (size_t)(GROW_S2 + b*NF_ + j) * H_;
        b1 = pb1; w2 = pw2; outp = sstep + s;
    } else if (wv < NSENT_ + NSTEP_ + NABD_) {
        int s = wv - NSENT_ - NSTEP_;
        int b = s / NF_, f = s % NF_;
        U = G + (size_t)(GROW_AT + b) * H_;
        V = G + (size_t)(GROW_AF + b*NF_ + f) * H_;
        b1 = ab1; w2 = aw2; outp = sabd + s;
    } else {
        int b = wv - NSENT_ - NSTEP_ - NABD_;
        U = G + (size_t)(GROW_CLS + b) * H_;
        V = nullptr;
        b1 = cb1; w2 = cw2; outp = scls + b;
    }

    float acc = 0.f;
    #pragma unroll
    for (int h = 0; h < 2; ++h) {
        int nb = h * 512 + lane * 8;
        uint4 uu = *(const uint4*)(U + nb);
        float us[8] = { bflo(uu.x), bfhi(uu.x), bflo(uu.y), bfhi(uu.y),
                        bflo(uu.z), bfhi(uu.z), bflo(uu.w), bfhi(uu.w) };
        if (V) {
            uint4 vv = *(const uint4*)(V + nb);
            us[0] += bflo(vv.x); us[1] += bfhi(vv.x);
            us[2] += bflo(vv.y); us[3] += bfhi(vv.y);
            us[4] += bflo(vv.z); us[5] += bfhi(vv.z);
            us[6] += bflo(vv.w); us[7] += bfhi(vv.w);
        }
        float4 bA = *(const float4*)(b1 + nb);
        float4 bB = *(const float4*)(b1 + nb + 4);
        float4 wA = *(const float4*)(w2 + nb);
        float4 wB = *(const float4*)(w2 + nb + 4);
        acc = fmaf(fmaxf(us[0] + bA.x, 0.f), wA.x, acc);
        acc = fmaf(fmaxf(us[1] + bA.y, 0.f), wA.y, acc);
        acc = fmaf(fmaxf(us[2] + bA.z, 0.f), wA.z, acc);
        acc = fmaf(fmaxf(us[3] + bA.w, 0.f), wA.w, acc);
        acc = fmaf(fmaxf(us[4] + bB.x, 0.f), wB.x, acc);
        acc = fmaf(fmaxf(us[5] + bB.y, 0.f), wB.y, acc);
        acc = fmaf(fmaxf(us[6] + bB.z, 0.f), wB.z, acc);
        acc = fmaf(fmaxf(us[7] + bB.w, 0.f), wB.w, acc);
    }
    #pragma unroll
    for (int msk = 1; msk < 64; msk <<= 1)
        acc += __shfl_xor(acc, msk);
    if (lane == 0) *outp = acc;
}

// ---------------------------------------------------------------------------
// Finalize: sigmoids, masked max/mean, lambda blend, 78-way softmax, output
// ---------------------------------------------------------------------------
__global__ __launch_bounds__(128) void finalize_kernel(
    const float* __restrict__ s_sent, const float* __restrict__ s_step,
    const float* __restrict__ s_abd, const float* __restrict__ s_cls,
    const float* __restrict__ mask, const float* __restrict__ lam,
    const float* __restrict__ sent_b2, const float* __restrict__ step_b2,
    const float* __restrict__ state_b2, const float* __restrict__ abd_b2,
    float* __restrict__ out)
{
    int b = blockIdx.x;
    int tid = threadIdx.x;
    __shared__ float fs[TNF_];
    __shared__ float sc[NP_ + NF_];
    __shared__ float mpf[NF_];
    __shared__ float smax, ssum;

    if (tid < TNF_) {
        float v = 1.f / (1.f + expf(-(s_sent[b*TNF_ + tid] + sent_b2[0])));
        fs[tid] = v;
        out[(size_t)b*OUTC_ + 1 + tid] = v;
    }
    if (tid < NP_)
        sc[tid] = s_step[b*NP_ + tid] + step_b2[0];
    else if (tid < NP_ + NF_)
        sc[tid] = s_abd[b*NF_ + (tid - NP_)] + abd_b2[0];
    __syncthreads();

    if (tid < NF_) {
        float m = -1e30f;
        for (int j = 0; j < T_; ++j)
            m = fmaxf(m, fs[tid*T_ + j] * mask[((size_t)b*NF_ + tid)*T_ + j]);
        mpf[tid] = m;
    }
    __syncthreads();

    if (tid == 0) {
        float sf = 0.f;
        for (int i = 0; i < NF_; ++i) sf += mpf[i];
        sf *= (1.f / NF_);
        float scls2 = 1.f / (1.f + expf(-(s_cls[b] + state_b2[0])));
        float l0 = lam[0], l1 = lam[1];
        float mx = fmaxf(l0, l1);
        float e0 = expf(l0 - mx), e1 = expf(l1 - mx);
        float w0 = e0 / (e0 + e1);
        out[(size_t)b*OUTC_] = w0 * sf + (1.f - w0) * scls2;
        float m2 = -1e30f;
        for (int i = 0; i < NP_ + NF_; ++i) m2 = fmaxf(m2, sc[i]);
        smax = m2;
    }
    __syncthreads();
    if (tid < NP_ + NF_) sc[tid] = expf(sc[tid] - smax);
    __syncthreads();
    if (tid == 0) {
        float s2 = 0.f;
        for (int i = 0; i < NP_ + NF_; ++i) s2 += sc[i];
        ssum = s2;
    }
    __syncthreads();
    if (tid < NP_ + NF_)
        out[(size_t)b*OUTC_ + 1 + TNF_ + tid] = sc[tid] / ssum;
}

// ---------------------------------------------------------------------------
extern "C" void kernel_launch(void* const* d_in, const int* in_sizes, int n_in,
                              void* d_out, int out_size, void* d_ws, size_t ws_size,
                              hipStream_t stream)
{
    (void)in_sizes; (void)n_in; (void)out_size; (void)ws_size;
    const float* seq  = (const float*)d_in[0];
    const float* cls  = (const float*)d_in[1];
    const int*   toff = (const int*)d_in[2];
    const int*   foff = (const int*)d_in[3];
    const float* mask = (const float*)d_in[4];
    const float* sw1  = (const float*)d_in[5];
    const float* sb1  = (const float*)d_in[6];
    const float* sw2  = (const float*)d_in[7];
    const float* sb2  = (const float*)d_in[8];
    const float* pw1  = (const float*)d_in[9];
    const float* pb1  = (const float*)d_in[10];
    const float* pw2  = (const float*)d_in[11];
    const float* pb2  = (const float*)d_in[12];
    const float* cw1  = (const float*)d_in[13];
    const float* cb1  = (const float*)d_in[14];
    const float* cw2  = (const float*)d_in[15];
    const float* cb2  = (const float*)d_in[16];
    const float* aw1  = (const float*)d_in[17];
    const float* ab1  = (const float*)d_in[18];
    const float* aw2  = (const float*)d_in[19];
    const float* ab2  = (const float*)d_in[20];
    const float* lam  = (const float*)d_in[21];

    char* wsb = (char*)d_ws;
    float*  tgt32 = (float*)wsb;                              // 1 MB
    float*  ssent = (float*)(wsb + (1u<<20));                 // 8128 floats
    float*  sstep = ssent + NSENT_;
    float*  sabd  = sstep + NSTEP_;
    float*  scls  = sabd + NABD_;
    ushort* Abf   = (ushort*)(wsb + (1u<<20) + 32768);        // 2.36 MB
    ushort* Wt    = Abf + (size_t)AROWS_ * H_;                // 14.68 MB
    ushort* G     = Wt + (size_t)7 * HH_;                     // 7.08 MB

    prep_kernel<<<1088 + 7*1024, 256, 0, stream>>>(
        seq, toff, foff, cls, sw1, pw1, aw1, cw1, tgt32, Abf, Wt);

    tside_kernel<<<B_, 256, 0, stream>>>(tgt32, Abf);

    gemm_bf16_kernel<<<dim3(54, 8), 256, 0, stream>>>(Abf, Wt, G);

    combine_kernel<<<(NWAVES_ + 3) / 4, 256, 0, stream>>>(
        G, sb1, sw2, pb1, pw2, ab1, aw2, cb1, cw2,
        ssent, sstep, sabd, scls);

    finalize_kernel<<<B_, 128, 0, stream>>>(
        ssent, sstep, sabd, scls, mask, lam, sb2, pb2, cb2, ab2, (float*)d_out);
}

// Round 6
// 62.455 us; speedup vs baseline: 10.4896x; 1.0448x over previous
//
#include <hip/hip_runtime.h>
#include <hip/hip_bf16.h>

// Problem constants
#define B_    64
#define S_    512
#define H_    1024
#define HH_   (H_*H_)
#define T_    4
#define NF_   12
#define TNF_  48      // T*NF
#define NP_   66      // NF*(NF-1)/2
#define OUTC_ 127     // 1 + 48 + 66 + 12

// score counts
#define NSENT_ (B_*TNF_)   // 3072
#define NSTEP_ (B_*NP_)    // 4224
#define NABD_  (B_*NF_)    // 768
#define NCLS_  (B_)        // 64
#define NWAVES_ (NSENT_+NSTEP_+NABD_+NCLS_)  // 8128

// A-buffer rows (bf16, row length 1024)
#define AROW_FCT   0      // 768 rows (b*12+f)
#define AROW_TGT   768    // 256 rows (b*4+t)
#define AROW_TSD   1024   // 64 rows
#define AROW_CLS   1088   // 64 rows
#define AROWS_PAD_ 1280   // incl. 128 pad rows for the cls 128-row tile

// G rows (bf16, row length 1024): fsent, s1, s2, af, tsent, at, cls
#define GROW_FSENT 0
#define GROW_S1    768
#define GROW_S2    1536
#define GROW_AF    2304
#define GROW_TSENT 3072
#define GROW_AT    3328
#define GROW_CLS   3392
#define GROWS_     3456

typedef __bf16 bf16x8 __attribute__((ext_vector_type(8)));
typedef float  f32x4  __attribute__((ext_vector_type(4)));
typedef __attribute__((address_space(1))) const unsigned int gcu32;
typedef __attribute__((address_space(3))) unsigned int lu32;

__device__ __forceinline__ ushort f2bf(float x) {
    union { float f; unsigned u; } c; c.f = x;
    unsigned r = c.u + 0x7fffu + ((c.u >> 16) & 1u);
    return (ushort)(r >> 16);
}
__device__ __forceinline__ float bflo(unsigned u) {
    union { unsigned u; float f; } c; c.u = u << 16; return c.f;
}
__device__ __forceinline__ float bfhi(unsigned u) {
    union { unsigned u; float f; } c; c.u = u & 0xffff0000u; return c.f;
}

// ---------------------------------------------------------------------------
// Prep (merged): blocks [0,1024) segment means -> bf16 A rows (+fp32 tgt),
//                blocks [1024,1088) cls cast, blocks [1088,8256) W1 transpose.
// ---------------------------------------------------------------------------
__global__ __launch_bounds__(256) void prep_kernel(
    const float* __restrict__ seq, const int* __restrict__ toffs,
    const int* __restrict__ foffs, const float* __restrict__ cls,
    const float* __restrict__ sw1, const float* __restrict__ pw1,
    const float* __restrict__ aw1, const float* __restrict__ cw1,
    float* __restrict__ tgt32, ushort* __restrict__ Abf,
    ushort* __restrict__ Wt)
{
    int blk = blockIdx.x;
    int tid = threadIdx.x;

    if (blk < 1024) {
        // ---- segment mean ----
        int b = blk >> 4;
        int k = blk & 15;
        int start, end, arow;
        float* dst32 = nullptr;
        if (k < T_) {
            start = toffs[(b*T_ + k)*2];
            end   = toffs[(b*T_ + k)*2 + 1];
            dst32 = tgt32 + (size_t)(b*T_ + k) * H_;
            arow  = AROW_TGT + b*T_ + k;
        } else {
            int f = k - T_;
            start = foffs[(b*NF_ + f)*2];
            end   = foffs[(b*NF_ + f)*2 + 1];
            arow  = AROW_FCT + b*NF_ + f;
        }
        int h0 = tid * 4;
        const float* base = seq + ((size_t)b * S_ + start) * H_ + h0;
        float4 s = make_float4(0.f, 0.f, 0.f, 0.f);
        int n = end - start;
        #pragma unroll 4
        for (int r = 0; r < n; ++r) {
            float4 v = *(const float4*)(base + (size_t)r * H_);
            s.x += v.x; s.y += v.y; s.z += v.z; s.w += v.w;
        }
        float inv = 1.f / (float)n;
        s.x *= inv; s.y *= inv; s.z *= inv; s.w *= inv;
        if (dst32) *(float4*)(dst32 + h0) = s;
        ushort4 q; q.x = f2bf(s.x); q.y = f2bf(s.y); q.z = f2bf(s.z); q.w = f2bf(s.w);
        *(ushort4*)(Abf + (size_t)arow * H_ + h0) = q;
    } else if (blk < 1088) {
        // ---- cls cast ----
        int b = blk - 1024;
        int h0 = tid * 4;
        float4 c = *(const float4*)(cls + (size_t)b * H_ + h0);
        ushort4 qc; qc.x = f2bf(c.x); qc.y = f2bf(c.y); qc.z = f2bf(c.z); qc.w = f2bf(c.w);
        *(ushort4*)(Abf + (size_t)(AROW_CLS + b) * H_ + h0) = qc;
    } else {
        // ---- transpose-cast 32x32 tile of one of 7 fp32 [1024][1024] blocks
        // src order: 0 sw1-top, 1 pw1-top, 2 pw1-bot, 3 aw1-bot, 4 sw1-bot,
        //            5 aw1-top, 6 cw1
        __shared__ float Tt[32][33];
        int idx2 = blk - 1088;
        int z = idx2 >> 10;
        int rem = idx2 & 1023;
        int k0 = (rem >> 5) * 32;
        int n0 = (rem & 31) * 32;
        const float* src;
        switch (z) {
            case 0: src = sw1; break;
            case 1: src = pw1; break;
            case 2: src = pw1 + HH_; break;
            case 3: src = aw1 + HH_; break;
            case 4: src = sw1 + HH_; break;
            case 5: src = aw1; break;
            default: src = cw1; break;
        }
        int ty = tid >> 3, tx = tid & 7;
        float4 v = *(const float4*)(src + (size_t)(k0 + ty) * H_ + n0 + tx*4);
        Tt[ty][tx*4 + 0] = v.x; Tt[ty][tx*4 + 1] = v.y;
        Tt[ty][tx*4 + 2] = v.z; Tt[ty][tx*4 + 3] = v.w;
        __syncthreads();
        int nx = ty, kx = tx;
        ushort4 q;
        q.x = f2bf(Tt[kx*4 + 0][nx]); q.y = f2bf(Tt[kx*4 + 1][nx]);
        q.z = f2bf(Tt[kx*4 + 2][nx]); q.w = f2bf(Tt[kx*4 + 3][nx]);
        *(ushort4*)(Wt + (size_t)z * HH_ + (size_t)(n0 + nx) * H_ + k0 + kx*4) = q;
    }
}

// tside (mean of fp32 tgt) -> bf16 row
__global__ __launch_bounds__(256) void tside_kernel(
    const float* __restrict__ tgt32, ushort* __restrict__ Abf)
{
    int b = blockIdx.x;
    int h0 = threadIdx.x * 4;
    float4 s = make_float4(0.f, 0.f, 0.f, 0.f);
    for (int t = 0; t < T_; ++t) {
        float4 v = *(const float4*)(tgt32 + (size_t)(b*T_ + t)*H_ + h0);
        s.x += v.x; s.y += v.y; s.z += v.z; s.w += v.w;
    }
    ushort4 q;
    q.x = f2bf(s.x*0.25f); q.y = f2bf(s.y*0.25f);
    q.z = f2bf(s.z*0.25f); q.w = f2bf(s.w*0.25f);
    *(ushort4*)(Abf + (size_t)(AROW_TSD + b) * H_ + h0) = q;
}

// ---------------------------------------------------------------------------
// Merged bf16 MFMA GEMM, counted-vmcnt pipeline (T3/T4).
// 128x128 tile, BK=32, depth-2 LDS double-buffer, raw s_barrier +
// s_waitcnt vmcnt(4) (never 0 in-loop). 4 waves (2x2), wave tile 64x64 =
// 4x4 frags of 16x16x32. Grid (28, 8) = 224 blocks.
// LDS chunk-swizzle: phys_chunk = c ^ ((row>>1)&3), pre-swizzled on the
// GLOBAL source address (rule #21), read with the same XOR.
// ---------------------------------------------------------------------------
__global__ __launch_bounds__(256) void gemm_bf16_kernel(
    const ushort* __restrict__ Abf, const ushort* __restrict__ Wt,
    ushort* __restrict__ G)
{
    __shared__ __align__(16) ushort As[2][128*32];
    __shared__ __align__(16) ushort Bs[2][128*32];

    int bx = blockIdx.x;
    int arow_base, wsel, grow_base, m0, vrows;
    if (bx < 24)      { int j = bx / 6; int mt = bx % 6; arow_base = AROW_FCT;
                        wsel = j; grow_base = j * 768; m0 = mt * 128; vrows = 128; }
    else if (bx < 26) { arow_base = AROW_TGT; wsel = 4; grow_base = GROW_TSENT;
                        m0 = (bx - 24) * 128; vrows = 128; }
    else if (bx == 26){ arow_base = AROW_TSD; wsel = 5; grow_base = GROW_AT;
                        m0 = 0; vrows = 64; }
    else              { arow_base = AROW_CLS; wsel = 6; grow_base = GROW_CLS;
                        m0 = 0; vrows = 64; }

    const int tid  = threadIdx.x;
    const int lane = tid & 63;
    const int w    = tid >> 6;        // 0..3
    const int wr   = w >> 1, wc = w & 1;
    const int n0   = blockIdx.y * 128;

    // ---- staging addresses (lane-constant, source pre-swizzled) ----
    const int srow = lane >> 2;                              // 0..15
    const int scol = ((lane & 3) ^ ((lane >> 3) & 3)) * 8;   // swizzled src chunk
    const ushort* gA0 = Abf + (size_t)(arow_base + m0 + w*16 + srow) * H_ + scol;
    const ushort* gA1 = gA0 + (size_t)64 * H_;
    const ushort* gB0 = Wt + (size_t)wsel * HH_
                        + (size_t)(n0 + w*16 + srow) * H_ + scol;
    const ushort* gB1 = gB0 + (size_t)64 * H_;
    // wave-uniform LDS bases (elements)
    const int ldsA0 = (0*64 + w*16) * 32, ldsA1 = (1*64 + w*16) * 32;

    // ---- fragment read offsets (swizzled, lane-constant) ----
    const int frr  = lane & 15;
    const int c0   = lane >> 4;
    const int swz  = (frr >> 1) & 3;
    const int offA = (wr*64 + frr) * 32 + (c0 ^ swz) * 8;   // elems
    const int offB = (wc*64 + frr) * 32 + (c0 ^ swz) * 8;

    f32x4 acc[4][4];
    #pragma unroll
    for (int i = 0; i < 4; ++i)
        #pragma unroll
        for (int j = 0; j < 4; ++j)
            acc[i][j] = (f32x4){0.f, 0.f, 0.f, 0.f};

    #define STAGE(buf, kstep) do {                                              \
        int kk_ = (kstep) < 32 ? (kstep) * 32 : 0;                              \
        __builtin_amdgcn_global_load_lds((gcu32*)(gA0 + kk_),                   \
            (lu32*)(As[buf] + ldsA0), 16, 0, 0);                                \
        __builtin_amdgcn_global_load_lds((gcu32*)(gA1 + kk_),                   \
            (lu32*)(As[buf] + ldsA1), 16, 0, 0);                                \
        __builtin_amdgcn_global_load_lds((gcu32*)(gB0 + kk_),                   \
            (lu32*)(Bs[buf] + ldsA0), 16, 0, 0);                                \
        __builtin_amdgcn_global_load_lds((gcu32*)(gB1 + kk_),                   \
            (lu32*)(Bs[buf] + ldsA1), 16, 0, 0);                                \
    } while (0)

    STAGE(0, 0);
    STAGE(1, 1);          // 8 loads outstanding

    #pragma unroll 1
    for (int t = 0; t < 32; ++t) {
        const int cur = t & 1;
        // wait my 4 oldest (buf cur) done; 4 (buf cur^1) stay in flight
        asm volatile("s_waitcnt vmcnt(4)" ::: "memory");
        __builtin_amdgcn_s_barrier();          // everyone's buf-cur writes done
        __builtin_amdgcn_sched_barrier(0);

        const ushort* pa = As[cur] + offA;
        const ushort* pb = Bs[cur] + offB;
        bf16x8 a0 = *(const bf16x8*)(pa);
        bf16x8 a1 = *(const bf16x8*)(pa + 16*32);
        bf16x8 a2 = *(const bf16x8*)(pa + 32*32);
        bf16x8 a3 = *(const bf16x8*)(pa + 48*32);
        bf16x8 b0 = *(const bf16x8*)(pb);
        bf16x8 b1 = *(const bf16x8*)(pb + 16*32);
        bf16x8 b2 = *(const bf16x8*)(pb + 32*32);
        bf16x8 b3 = *(const bf16x8*)(pb + 48*32);

        asm volatile("s_waitcnt lgkmcnt(0)" ::: "memory");  // my reads done
        __builtin_amdgcn_s_barrier();          // everyone's reads of cur done
        __builtin_amdgcn_sched_barrier(0);

        if (t < 30) STAGE(cur, t + 2);         // overwrite cur for t+2

        bf16x8 av[4] = {a0, a1, a2, a3};
        bf16x8 bv[4] = {b0, b1, b2, b3};
        #pragma unroll
        for (int i = 0; i < 4; ++i)
            #pragma unroll
            for (int j = 0; j < 4; ++j)
                acc[i][j] = __builtin_amdgcn_mfma_f32_16x16x32_bf16(
                    av[i], bv[j], acc[i][j], 0, 0, 0);
    }
    #undef STAGE

    // C/D layout: col = lane&15, row = (lane>>4)*4 + reg   [verified m89]
    const int r0 = (lane >> 4) * 4;
    const int cc = lane & 15;
    #pragma unroll
    for (int i = 0; i < 4; ++i) {
        int lrow = wr*64 + i*16 + r0;
        if (lrow >= vrows) continue;
        #pragma unroll
        for (int r = 0; r < 4; ++r) {
            size_t gr = (size_t)(grow_base + m0 + lrow + r) * H_ + n0 + wc*64 + cc;
            #pragma unroll
            for (int j = 0; j < 4; ++j)
                G[gr + j*16] = f2bf(acc[i][j][r]);
        }
    }
}

// ---------------------------------------------------------------------------
// Combine: one wave per score. score = sum_n relu(U[n](+V[n])+b1[n])*w2[n]
// ---------------------------------------------------------------------------
__global__ __launch_bounds__(256) void combine_kernel(
    const ushort* __restrict__ G,
    const float* __restrict__ sb1, const float* __restrict__ sw2,
    const float* __restrict__ pb1, const float* __restrict__ pw2,
    const float* __restrict__ ab1, const float* __restrict__ aw2,
    const float* __restrict__ cb1, const float* __restrict__ cw2,
    float* __restrict__ ssent, float* __restrict__ sstep,
    float* __restrict__ sabd, float* __restrict__ scls)
{
    int wv = blockIdx.x * 4 + (threadIdx.x >> 6);
    int lane = threadIdx.x & 63;
    if (wv >= NWAVES_) return;

    const ushort *U, *V;
    const float *b1, *w2;
    float* outp;
    if (wv < NSENT_) {
        int b = wv / TNF_, q = wv % TNF_;
        int t = q / NF_, f = q % NF_;
        U = G + (size_t)(GROW_FSENT + b*NF_ + f) * H_;
        V = G + (size_t)(GROW_TSENT + b*T_ + t) * H_;
        b1 = sb1; w2 = sw2; outp = ssent + wv;
    } else if (wv < NSENT_ + NSTEP_) {
        int s = wv - NSENT_;
        int b = s / NP_, p = s % NP_;
        int i = 0, rem = p, cnt = NF_ - 1;
        while (rem >= cnt) { rem -= cnt; --cnt; ++i; }
        int j = i + 1 + rem;
        U = G + (size_t)(GROW_S1 + b*NF_ + i) * H_;
        V = G + (size_t)(GROW_S2 + b*NF_ + j) * H_;
        b1 = pb1; w2 = pw2; outp = sstep + s;
    } else if (wv < NSENT_ + NSTEP_ + NABD_) {
        int s = wv - NSENT_ - NSTEP_;
        int b = s / NF_, f = s % NF_;
        U = G + (size_t)(GROW_AT + b) * H_;
        V = G + (size_t)(GROW_AF + b*NF_ + f) * H_;
        b1 = ab1; w2 = aw2; outp = sabd + s;
    } else {
        int b = wv - NSENT_ - NSTEP_ - NABD_;
        U = G + (size_t)(GROW_CLS + b) * H_;
        V = nullptr;
        b1 = cb1; w2 = cw2; outp = scls + b;
    }

    float acc = 0.f;
    #pragma unroll
    for (int h = 0; h < 2; ++h) {
        int nb = h * 512 + lane * 8;
        uint4 uu = *(const uint4*)(U + nb);
        float us[8] = { bflo(uu.x), bfhi(uu.x), bflo(uu.y), bfhi(uu.y),
                        bflo(uu.z), bfhi(uu.z), bflo(uu.w), bfhi(uu.w) };
        if (V) {
            uint4 vv = *(const uint4*)(V + nb);
            us[0] += bflo(vv.x); us[1] += bfhi(vv.x);
            us[2] += bflo(vv.y); us[3] += bfhi(vv.y);
            us[4] += bflo(vv.z); us[5] += bfhi(vv.z);
            us[6] += bflo(vv.w); us[7] += bfhi(vv.w);
        }
        float4 bA = *(const float4*)(b1 + nb);
        float4 bB = *(const float4*)(b1 + nb + 4);
        float4 wA = *(const float4*)(w2 + nb);
        float4 wB = *(const float4*)(w2 + nb + 4);
        acc = fmaf(fmaxf(us[0] + bA.x, 0.f), wA.x, acc);
        acc = fmaf(fmaxf(us[1] + bA.y, 0.f), wA.y, acc);
        acc = fmaf(fmaxf(us[2] + bA.z, 0.f), wA.z, acc);
        acc = fmaf(fmaxf(us[3] + bA.w, 0.f), wA.w, acc);
        acc = fmaf(fmaxf(us[4] + bB.x, 0.f), wB.x, acc);
        acc = fmaf(fmaxf(us[5] + bB.y, 0.f), wB.y, acc);
        acc = fmaf(fmaxf(us[6] + bB.z, 0.f), wB.z, acc);
        acc = fmaf(fmaxf(us[7] + bB.w, 0.f), wB.w, acc);
    }
    #pragma unroll
    for (int msk = 1; msk < 64; msk <<= 1)
        acc += __shfl_xor(acc, msk);
    if (lane == 0) *outp = acc;
}

// ---------------------------------------------------------------------------
// Finalize: sigmoids, masked max/mean, lambda blend, 78-way softmax, output
// ---------------------------------------------------------------------------
__global__ __launch_bounds__(128) void finalize_kernel(
    const float* __restrict__ s_sent, const float* __restrict__ s_step,
    const float* __restrict__ s_abd, const float* __restrict__ s_cls,
    const float* __restrict__ mask, const float* __restrict__ lam,
    const float* __restrict__ sent_b2, const float* __restrict__ step_b2,
    const float* __restrict__ state_b2, const float* __restrict__ abd_b2,
    float* __restrict__ out)
{
    int b = blockIdx.x;
    int tid = threadIdx.x;
    __shared__ float fs[TNF_];
    __shared__ float sc[NP_ + NF_];
    __shared__ float mpf[NF_];
    __shared__ float smax, ssum;

    if (tid < TNF_) {
        float v = 1.f / (1.f + expf(-(s_sent[b*TNF_ + tid] + sent_b2[0])));
        fs[tid] = v;
        out[(size_t)b*OUTC_ + 1 + tid] = v;
    }
    if (tid < NP_)
        sc[tid] = s_step[b*NP_ + tid] + step_b2[0];
    else if (tid < NP_ + NF_)
        sc[tid] = s_abd[b*NF_ + (tid - NP_)] + abd_b2[0];
    __syncthreads();

    if (tid < NF_) {
        float m = -1e30f;
        for (int j = 0; j < T_; ++j)
            m = fmaxf(m, fs[tid*T_ + j] * mask[((size_t)b*NF_ + tid)*T_ + j]);
        mpf[tid] = m;
    }
    __syncthreads();

    if (tid == 0) {
        float sf = 0.f;
        for (int i = 0; i < NF_; ++i) sf += mpf[i];
        sf *= (1.f / NF_);
        float scls2 = 1.f / (1.f + expf(-(s_cls[b] + state_b2[0])));
        float l0 = lam[0], l1 = lam[1];
        float mx = fmaxf(l0, l1);
        float e0 = expf(l0 - mx), e1 = expf(l1 - mx);
        float w0 = e0 / (e0 + e1);
        out[(size_t)b*OUTC_] = w0 * sf + (1.f - w0) * scls2;
        float m2 = -1e30f;
        for (int i = 0; i < NP_ + NF_; ++i) m2 = fmaxf(m2, sc[i]);
        smax = m2;
    }
    __syncthreads();
    if (tid < NP_ + NF_) sc[tid] = expf(sc[tid] - smax);
    __syncthreads();
    if (tid == 0) {
        float s2 = 0.f;
        for (int i = 0; i < NP_ + NF_; ++i) s2 += sc[i];
        ssum = s2;
    }
    __syncthreads();
    if (tid < NP_ + NF_)
        out[(size_t)b*OUTC_ + 1 + TNF_ + tid] = sc[tid] / ssum;
}

// ---------------------------------------------------------------------------
extern "C" void kernel_launch(void* const* d_in, const int* in_sizes, int n_in,
                              void* d_out, int out_size, void* d_ws, size_t ws_size,
                              hipStream_t stream)
{
    (void)in_sizes; (void)n_in; (void)out_size; (void)ws_size;
    const float* seq  = (const float*)d_in[0];
    const float* cls  = (const float*)d_in[1];
    const int*   toff = (const int*)d_in[2];
    const int*   foff = (const int*)d_in[3];
    const float* mask = (const float*)d_in[4];
    const float* sw1  = (const float*)d_in[5];
    const float* sb1  = (const float*)d_in[6];
    const float* sw2  = (const float*)d_in[7];
    const float* sb2  = (const float*)d_in[8];
    const float* pw1  = (const float*)d_in[9];
    const float* pb1  = (const float*)d_in[10];
    const float* pw2  = (const float*)d_in[11];
    const float* pb2  = (const float*)d_in[12];
    const float* cw1  = (const float*)d_in[13];
    const float* cb1  = (const float*)d_in[14];
    const float* cw2  = (const float*)d_in[15];
    const float* cb2  = (const float*)d_in[16];
    const float* aw1  = (const float*)d_in[17];
    const float* ab1  = (const float*)d_in[18];
    const float* aw2  = (const float*)d_in[19];
    const float* ab2  = (const float*)d_in[20];
    const float* lam  = (const float*)d_in[21];

    char* wsb = (char*)d_ws;
    float*  tgt32 = (float*)wsb;                              // 1 MB
    float*  ssent = (float*)(wsb + (1u<<20));                 // 8128 floats
    float*  sstep = ssent + NSENT_;
    float*  sabd  = sstep + NSTEP_;
    float*  scls  = sabd + NABD_;
    ushort* Abf   = (ushort*)(wsb + (1u<<20) + 32768);        // 1280 rows bf16
    ushort* Wt    = Abf + (size_t)AROWS_PAD_ * H_;            // 14.68 MB
    ushort* G     = Wt + (size_t)7 * HH_;                     // 7.08 MB

    prep_kernel<<<1088 + 7*1024, 256, 0, stream>>>(
        seq, toff, foff, cls, sw1, pw1, aw1, cw1, tgt32, Abf, Wt);

    tside_kernel<<<B_, 256, 0, stream>>>(tgt32, Abf);

    gemm_bf16_kernel<<<dim3(28, 8), 256, 0, stream>>>(Abf, Wt, G);

    combine_kernel<<<(NWAVES_ + 3) / 4, 256, 0, stream>>>(
        G, sb1, sw2, pb1, pw2, ab1, aw2, cb1, cw2,
        ssent, sstep, sabd, scls);

    finalize_kernel<<<B_, 128, 0, stream>>>(
        ssent, sstep, sabd, scls, mask, lam, sb2, pb2, cb2, ab2, (float*)d_out);
}